// Round 12
// baseline (72.698 us; speedup 1.0000x reference)
//
#include <hip/hip_runtime.h>
#include <hip/hip_bf16.h>
#include <math.h>

// SDGCN fused, v12 = v11 (swizzled single-barrier double-buffer) with the
// symmetric max/sum reductions reverted from raw-asm permlane32_swap to the
// verified __shfl_xor(.,32) path.
// ROOT CAUSE of v10/v11 failures: PLSWAP(ta,tb) with ta==tb initialized from
// the same value lets regalloc coalesce both "+v" operands into ONE register
// -> v_permlane32_swap v5,v5 self-swap -> each lane-half got the OTHER
// half's partial max -> mrun diverged between halves -> per-column-subset
// softmax scales -> order-1 H error (LN only cancels per-row-uniform scale).
//
// mfma_f32_32x32x16_bf16 layouts (m74/m101-verified C/D; standard A/B):
//   A-frag: lane l holds A[l&31][(l>>5)*8+e]
//   B-frag: lane l holds B[(l>>5)*8+e][l&31]
//   C/D:    lane l, reg r holds C[(r&3)+8*(r>>2)+4*(l>>5)][l&31]

typedef short bf16x8 __attribute__((ext_vector_type(8)));
typedef float f32x4  __attribute__((ext_vector_type(4)));
typedef float f32x16 __attribute__((ext_vector_type(16)));
typedef int   i32x4  __attribute__((ext_vector_type(4)));

constexpr int kN = 1024;
constexpr int kD = 64;
constexpr size_t kPlane    = 48u * 1024u * 64u;
constexpr size_t kAfShorts = 16u * 32u * 2048u;

#define MFMA32(a,b,c) __builtin_amdgcn_mfma_f32_32x32x16_bf16((a),(b),(c),0,0,0)
#define MFMA16(a,b,c) __builtin_amdgcn_mfma_f32_16x16x32_bf16((a),(b),(c),0,0,0)

__device__ __forceinline__ void splitv(float v, short& h, short& l) {
  unsigned u = __float_as_uint(v);
  h = (short)(u >> 16);
  float hf = __uint_as_float(u & 0xFFFF0000u);
  l = (short)(__float_as_uint(v - hf) >> 16);
}

__device__ __forceinline__ unsigned pkbf(float a, float b) {
  return (__float_as_uint(a) >> 16) | (__float_as_uint(b) & 0xFFFF0000u);
}

// ---------------- pre-pass 1 (verified): X -> bf16 hi/lo planes -----------
__global__ __launch_bounds__(256)
void presplit(const float* __restrict__ X, short* __restrict__ Xh,
              short* __restrict__ Xl, short* __restrict__ XTh)
{
  __shared__ short Sh[64][68], Sl[64][68];
  const int t  = threadIdx.x;
  const int bt = blockIdx.x >> 4;
  const int mb = blockIdx.x & 15;
  const size_t base = (size_t)bt * 65536 + (size_t)mb * 64 * 64;

#pragma unroll
  for (int k = 0; k < 4; ++k) {
    int idx = t + k * 256;
    int row = idx >> 4;
    int c4  = (idx & 15) * 4;
    float4 v = *(const float4*)(X + base + row * 64 + c4);
    short h0,l0,h1,l1,h2,l2,h3,l3;
    splitv(v.x, h0, l0); splitv(v.y, h1, l1);
    splitv(v.z, h2, l2); splitv(v.w, h3, l3);
    short4 hv = make_short4(h0, h1, h2, h3);
    short4 lv = make_short4(l0, l1, l2, l3);
    *(short4*)(Xh + base + row * 64 + c4) = hv;
    *(short4*)(Xl + base + row * 64 + c4) = lv;
    *(short4*)&Sh[row][c4] = hv;
    *(short4*)&Sl[row][c4] = lv;
  }
  __syncthreads();

  const size_t tbase = (size_t)bt * 65536 + (size_t)mb * 64;
#pragma unroll
  for (int k = 0; k < 2; ++k) {
    int idx = t + k * 256;
    int d   = idx >> 3;
    int m8  = (idx & 7) * 8;
    bf16x8 hv;
#pragma unroll
    for (int j = 0; j < 8; ++j) hv[j] = Sh[m8 + j][d];
    *(bf16x8*)(XTh + tbase + (size_t)d * 1024 + m8) = hv;
  }
}

// ---------------- pre-pass 2 (verified): A -> bf16 fragment order ---------
__global__ __launch_bounds__(256)
void prearr_Abf(const float* __restrict__ A, short* __restrict__ Af)
{
  const int qt  = blockIdx.x >> 5;
  const int gks = blockIdx.x & 31;
  const int kb  = gks * 32;
  const int s   = threadIdx.x;
  short* dst = Af + ((size_t)(qt * 32 + gks) * 2048);

  const int qw = s >> 7;
  const int ln = (s >> 1) & 63;
  const int p  = s & 1;
  const int q  = qt * 64 + qw * 32 + (ln & 31);
  const int h  = ln >> 5;
  const int k0 = kb + 16 * p + 4 * h;
  float4 f0 = *(const float4*)(A + (size_t)q * kN + k0);
  float4 f1 = *(const float4*)(A + (size_t)q * kN + k0 + 8);
  i32x4 u;
  u[0] = (int)pkbf(f0.x, f0.y); u[1] = (int)pkbf(f0.z, f0.w);
  u[2] = (int)pkbf(f1.x, f1.y); u[3] = (int)pkbf(f1.z, f1.w);
  *(i32x4*)(dst + (size_t)qw * 1024 + ln * 16 + p * 8) = u;
}

// ---------------- main fused kernel ----------------
template<int AMODE>
__global__ __launch_bounds__(256)
void sdgcn_v12(const float* __restrict__ X, const float* __restrict__ A,
               const float* __restrict__ W, const float* __restrict__ gamma,
               const float* __restrict__ beta, float* __restrict__ out,
               const short* __restrict__ Xh, const short* __restrict__ Xl,
               const short* __restrict__ XTh, const short* __restrict__ Af)
{
  // LDS 49152B = 2 bufs x 2 kg x {Kh[32*64], Kl[32*64], Vt[64*32]} shorts,
  // XOR-swizzled at 8-short granularity (no pads).
  // post-loop union: aM/aZ/aF @0 (1792B), Har[64][68] f32 @1792.
  __shared__ __align__(16) unsigned char LB[49152];

  const int t    = threadIdx.x;
  const int wave = t >> 6;
  const int lane = t & 63;
  const int kg   = wave >> 1;
  const int qw   = wave & 1;
  const int half = lane >> 5;
  const int l31  = lane & 31;
  const int bid  = blockIdx.x;
  const int swz  = (bid & 7) * 96 + (bid >> 3);   // XCD-chunked (768 = 8*96)
  const int bt   = swz >> 4;
  const int qt   = swz & 15;
  const int qblk = qt * 64;
  const size_t xb = (size_t)bt * 65536;

  short* Kh0 = (short*)(LB + kg * 12288);
  short* Kl0 = Kh0 + 2048;
  short* Vt0 = Kh0 + 4096;
  short* Kh1 = (short*)(LB + 24576 + kg * 12288);
  short* Kl1 = Kh1 + 2048;
  short* Vt1 = Kh1 + 4096;
  float* aM  = (float*)LB;            // [2][64]
  float* aZ  = aM + 128;
  float* aF  = aZ + 128;              // [3][64]
  float* Har = (float*)(LB + 1792);   // [64][68]

  // ---- Q B-frags
  const int qmine = qblk + qw * 32 + l31;
  bf16x8 qh[4], qlo[4];
#pragma unroll
  for (int c = 0; c < 4; ++c) {
    const size_t off = xb + (size_t)qmine * kD + 16 * c + half * 8;
    qh[c]  = *(const bf16x8*)(Xh + off);
    qlo[c] = *(const bf16x8*)(Xl + off);
  }

  f32x16 o0, o1;
#pragma unroll
  for (int r = 0; r < 16; ++r) { o0[r] = 0.f; o1[r] = 0.f; }
  float mrun = -INFINITY, Z = 0.f;

  const int tg = t & 127;

  auto ldK = [&](int kb, int j, bf16x8& h, bf16x8& l) {
    int ck = tg + 128 * j; int kr = ck >> 3; int kc = (ck & 7) * 8;
    size_t off = xb + (size_t)(kb + kr) * kD + kc;
    h = *(const bf16x8*)(Xh + off);
    l = *(const bf16x8*)(Xl + off);
  };
  auto ldV = [&](int kb, int j, bf16x8& h) {
    int cv = tg + 128 * j; int vd = cv >> 2; int vm = (cv & 3) * 8;
    h = *(const bf16x8*)(XTh + xb + (size_t)vd * 1024 + kb + vm);
  };
  auto stK = [&](short* Kh, short* Kl, int j, bf16x8 h, bf16x8 l) {
    int ck = tg + 128 * j; int kr = ck >> 3; int u = ck & 7;
    int off = kr * 64 + ((u ^ (kr & 7)) << 3);
    *(bf16x8*)&Kh[off] = h;
    *(bf16x8*)&Kl[off] = l;
  };
  auto stV = [&](short* Vt, int j, bf16x8 h) {
    int cv = tg + 128 * j; int vd = cv >> 2; int u = cv & 3;
    int off = vd * 32 + ((u ^ (vd & 3)) << 3);
    *(bf16x8*)&Vt[off] = h;
  };

  i32x4 aA = {0,0,0,0}, aB = {0,0,0,0};

  auto compute = [&](int ks, const short* Khg, const short* Klg,
                     const short* Vtg, bool pfA) {
    const int kb = kg * 512 + ks * 32;

    i32x4 naA = {0,0,0,0}, naB = {0,0,0,0};
    if (AMODE == 1 && pfA) {
      const short* Ab = Af + ((size_t)(qt * 32 + kg * 16 + ks + 1) * 2048)
                           + (size_t)qw * 1024 + (lane << 4);
      naA = *(const i32x4*)(Ab);
      naB = *(const i32x4*)(Ab + 8);
    }

    float agv[16];
    if (AMODE == 1) {
      unsigned u[8] = {(unsigned)aA[0],(unsigned)aA[1],(unsigned)aA[2],(unsigned)aA[3],
                       (unsigned)aB[0],(unsigned)aB[1],(unsigned)aB[2],(unsigned)aB[3]};
#pragma unroll
      for (int m = 0; m < 8; ++m) {
        agv[2*m]   = __uint_as_float(u[m] << 16);
        agv[2*m+1] = __uint_as_float(u[m] & 0xFFFF0000u);
      }
    } else {
      const float* Arow = A + (size_t)qmine * kN + kb + 4 * half;
      float4 ag0 = *(const float4*)(Arow);
      float4 ag1 = *(const float4*)(Arow + 8);
      float4 ag2 = *(const float4*)(Arow + 16);
      float4 ag3 = *(const float4*)(Arow + 24);
#pragma unroll
      for (int e = 0; e < 4; ++e) {
        agv[e] = ag0[e]; agv[4+e] = ag1[e]; agv[8+e] = ag2[e]; agv[12+e] = ag3[e];
      }
    }

    // ---- QK^T swapped (swizzled reads): lane holds S[k_local(r,half)][q=l31]
    f32x16 sa;
#pragma unroll
    for (int r = 0; r < 16; ++r) sa[r] = 0.f;
    __builtin_amdgcn_s_setprio(1);
#pragma unroll
    for (int c = 0; c < 4; ++c) {
      const int off = l31 * 64 + (((2 * c + half) ^ (l31 & 7)) << 3);
      bf16x8 kh = *(const bf16x8*)&Khg[off];
      bf16x8 kl = *(const bf16x8*)&Klg[off];
      sa = MFMA32(kh, qh[c],  sa);
      sa = MFMA32(kh, qlo[c], sa);
      sa = MFMA32(kl, qh[c],  sa);
    }
    __builtin_amdgcn_s_setprio(0);

    // ---- defer-max online softmax (verified shfl_xor cross-half reduce)
    float sm = sa[0];
#pragma unroll
    for (int r = 1; r < 16; ++r) sm = fmaxf(sm, sa[r]);
    sm = fmaxf(sm, __shfl_xor(sm, 32, 64));
    if (__any(sm > mrun + 8.f)) {
      const float nm = fmaxf(mrun, sm);
      const float f  = __expf(mrun - nm);   // 0 on first tile
      mrun = nm; Z *= f;
#pragma unroll
      for (int r = 0; r < 16; ++r) {
        const float fr = __shfl(f, (r & 3) + 8 * (r >> 2) + 4 * half, 64);
        o0[r] *= fr; o1[r] *= fr;
      }
    }
    float zt = 0.f;
    float pa[16];
#pragma unroll
    for (int r = 0; r < 16; ++r) {
      const float pv = __expf(sa[r] - mrun);
      zt += pv;
      pa[r] = pv * agv[r];
    }
    zt += __shfl_xor(zt, 32, 64);
    Z += zt;

    // ---- pack gated P + cross-half exchange (v9-verified shfl+select path)
    unsigned du[8], su[8];
#pragma unroll
    for (int j = 0; j < 8; ++j) du[j] = pkbf(pa[2*j], pa[2*j+1]);
#pragma unroll
    for (int j = 0; j < 8; ++j) su[j] = (unsigned)__shfl_xor((int)du[j], 32, 64);
    const bool lo = (half == 0);
    i32x4 w0, w1;
    w0[0] = lo ? du[0] : su[2]; w0[1] = lo ? du[1] : su[3];
    w0[2] = lo ? su[0] : du[2]; w0[3] = lo ? su[1] : du[3];
    w1[0] = lo ? du[4] : su[6]; w1[1] = lo ? du[5] : su[7];
    w1[2] = lo ? su[4] : du[6]; w1[3] = lo ? su[5] : du[7];
    bf16x8 pf0 = *(bf16x8*)&w0;
    bf16x8 pf1 = *(bf16x8*)&w1;

    // ---- PV (swizzled V reads): O[q][d] += P[q][k] V[k][d]
    {
      const int dxa = l31 & 3;
      bf16x8 v0 = *(const bf16x8*)&Vtg[l31 * 32 + ((half ^ dxa) << 3)];
      bf16x8 v1 = *(const bf16x8*)&Vtg[l31 * 32 + (((2 + half) ^ dxa) << 3)];
      bf16x8 v2 = *(const bf16x8*)&Vtg[(32 + l31) * 32 + ((half ^ dxa) << 3)];
      bf16x8 v3 = *(const bf16x8*)&Vtg[(32 + l31) * 32 + (((2 + half) ^ dxa) << 3)];
      __builtin_amdgcn_s_setprio(1);
      o0 = MFMA32(pf0, v0, o0);
      o0 = MFMA32(pf1, v1, o0);
      o1 = MFMA32(pf0, v2, o1);
      o1 = MFMA32(pf1, v3, o1);
      __builtin_amdgcn_s_setprio(0);
    }
    aA = naA; aB = naB;
  };

  // ---- prologue: stage tile 0 -> buf0; load A(step 0)
  {
    bf16x8 a0,a1,b0,b1,c0,d0;
    ldK(kg * 512, 0, a0, a1); ldK(kg * 512, 1, b0, b1);
    ldV(kg * 512, 0, c0);     ldV(kg * 512, 1, d0);
    stK(Kh0, Kl0, 0, a0, a1); stK(Kh0, Kl0, 1, b0, b1);
    stV(Vt0, 0, c0);          stV(Vt0, 1, d0);
  }
  if (AMODE == 1) {
    const short* Ab = Af + ((size_t)(qt * 32 + kg * 16) * 2048)
                         + (size_t)qw * 1024 + (lane << 4);
    aA = *(const i32x4*)(Ab);
    aB = *(const i32x4*)(Ab + 8);
  }
  __syncthreads();

  for (int ks = 0; ks < 16; ks += 2) {
    // phase A: compute tile ks (buf0); stage tile ks+1 -> buf1
    bf16x8 k0h,k0l,k1h,k1l,vr0,vr1;
    ldK(kg * 512 + (ks + 1) * 32, 0, k0h, k0l);
    ldK(kg * 512 + (ks + 1) * 32, 1, k1h, k1l);
    ldV(kg * 512 + (ks + 1) * 32, 0, vr0);
    ldV(kg * 512 + (ks + 1) * 32, 1, vr1);
    compute(ks, Kh0, Kl0, Vt0, true);
    stK(Kh1, Kl1, 0, k0h, k0l); stK(Kh1, Kl1, 1, k1h, k1l);
    stV(Vt1, 0, vr0);           stV(Vt1, 1, vr1);
    __syncthreads();

    // phase B: compute tile ks+1 (buf1); stage tile ks+2 -> buf0
    const bool more = (ks + 2) < 16;
    if (more) {
      ldK(kg * 512 + (ks + 2) * 32, 0, k0h, k0l);
      ldK(kg * 512 + (ks + 2) * 32, 1, k1h, k1l);
      ldV(kg * 512 + (ks + 2) * 32, 0, vr0);
      ldV(kg * 512 + (ks + 2) * 32, 1, vr1);
    }
    compute(ks + 1, Kh1, Kl1, Vt1, more);
    if (more) {
      stK(Kh0, Kl0, 0, k0h, k0l); stK(Kh0, Kl0, 1, k1h, k1l);
      stV(Vt0, 0, vr0);           stV(Vt0, 1, vr1);
    }
    __syncthreads();
  }

  // ================= split-K merge (v5-verified) =================
  if (lane < 32) {
    aM[kg * 64 + qw * 32 + l31] = mrun;
    aZ[kg * 64 + qw * 32 + l31] = Z;
  }
  if (kg == 1) {
#pragma unroll
    for (int r = 0; r < 16; ++r) {
      const int qq = qw * 32 + (r & 3) + 8 * (r >> 2) + 4 * half;
      Har[qq * 68 + l31]      = o0[r];
      Har[qq * 68 + l31 + 32] = o1[r];
    }
  }
  __syncthreads();
  if (kg == 1 && lane < 32) {
    const int q = qw * 32 + l31;
    const float ma = aM[q], mb = mrun;
    const float m  = fmaxf(ma, mb);
    const float fa = __expf(ma - m), fb = __expf(mb - m);
    const float Zs = aZ[q] * fa + Z * fb;
    aF[q]       = fa;
    aF[64 + q]  = fb;
    aF[128 + q] = 1.0f / (8.0f * Zs);   // sqrt(64)=8
  }
  __syncthreads();
  if (kg == 0) {
#pragma unroll
    for (int r = 0; r < 16; ++r) {
      const int qq = qw * 32 + (r & 3) + 8 * (r >> 2) + 4 * half;
      const float fa = aF[qq], fb = aF[64 + qq];
      Har[qq * 68 + l31]      = o0[r] * fa + Har[qq * 68 + l31]      * fb;
      Har[qq * 68 + l31 + 32] = o1[r] * fa + Har[qq * 68 + l31 + 32] * fb;
    }
  }
  __syncthreads();

  // ================= epilogue (v2-verified 16x16 path) =================
  const int g  = lane >> 4;
  const int ql = lane & 15;
  const int er = wave * 16;
  const float i8z = aF[128 + er + ql];

  bf16x8 hh[2], hl[2];
#pragma unroll
  for (int kk = 0; kk < 2; ++kk) {
    const float* hp = &Har[(er + ql) * 68 + kk * 32 + g * 8];
    float4 v0 = *(const float4*)hp;
    float4 v1 = *(const float4*)(hp + 4);
    float v[8] = {v0.x*i8z, v0.y*i8z, v0.z*i8z, v0.w*i8z,
                  v1.x*i8z, v1.y*i8z, v1.z*i8z, v1.w*i8z};
#pragma unroll
    for (int e = 0; e < 8; ++e) { short a, b; splitv(v[e], a, b); hh[kk][e] = a; hl[kk][e] = b; }
  }

  f32x4 lin[4];
#pragma unroll
  for (int c = 0; c < 4; ++c) {
    bf16x8 wh[2], wl[2];
#pragma unroll
    for (int kk = 0; kk < 2; ++kk) {
      const float* wp = W + (size_t)(c * 16 + ql) * kD + kk * 32 + g * 8;
      float4 v0 = *(const float4*)wp;
      float4 v1 = *(const float4*)(wp + 4);
      float v[8] = {v0.x, v0.y, v0.z, v0.w, v1.x, v1.y, v1.z, v1.w};
#pragma unroll
      for (int e = 0; e < 8; ++e) { short a, b; splitv(v[e], a, b); wh[kk][e] = a; wl[kk][e] = b; }
    }
    f32x4 acc = {0.f, 0.f, 0.f, 0.f};
    acc = MFMA16(hh[0], wh[0], acc);
    acc = MFMA16(hh[1], wh[1], acc);
    acc = MFMA16(hh[0], wl[0], acc);
    acc = MFMA16(hh[1], wl[1], acc);
    acc = MFMA16(hl[0], wh[0], acc);
    acc = MFMA16(hl[1], wh[1], acc);
    lin[c] = acc;
  }

  float rl[4][4];
#pragma unroll
  for (int c = 0; c < 4; ++c)
#pragma unroll
    for (int r = 0; r < 4; ++r) rl[c][r] = fmaxf(lin[c][r], 0.f);

  float mu[4], rstd[4];
#pragma unroll
  for (int r = 0; r < 4; ++r) {
    float s1 = rl[0][r] + rl[1][r] + rl[2][r] + rl[3][r];
    float s2 = rl[0][r]*rl[0][r] + rl[1][r]*rl[1][r] + rl[2][r]*rl[2][r] + rl[3][r]*rl[3][r];
#pragma unroll
    for (int off = 1; off < 16; off <<= 1) {
      s1 += __shfl_xor(s1, off, 64);
      s2 += __shfl_xor(s2, off, 64);
    }
    mu[r] = s1 * (1.f / 64.f);
    const float var = s2 * (1.f / 64.f) - mu[r] * mu[r];
    rstd[r] = rsqrtf(var + 1e-5f);
  }

#pragma unroll
  for (int c = 0; c < 4; ++c) {
    const float gm = gamma[c * 16 + ql];
    const float bb = beta[c * 16 + ql];
#pragma unroll
    for (int r = 0; r < 4; ++r) {
      const int qrow = qblk + er + 4 * g + r;
      const size_t off = ((size_t)bt * kN + qrow) * kD + c * 16 + ql;
      out[off] = (rl[c][r] - mu[r]) * rstd[r] * gm + bb + X[off];
    }
  }
}

extern "C" void kernel_launch(void* const* d_in, const int* in_sizes, int n_in,
                              void* d_out, int out_size, void* d_ws, size_t ws_size,
                              hipStream_t stream) {
  const float* X     = (const float*)d_in[0];
  const float* A     = (const float*)d_in[1];
  const float* W     = (const float*)d_in[2];
  const float* gamma = (const float*)d_in[3];
  const float* beta  = (const float*)d_in[4];
  float* out = (float*)d_out;

  short* Xh  = (short*)d_ws;
  short* Xl  = Xh  + kPlane;
  short* XTh = Xl  + kPlane;
  short* Af  = XTh + kPlane;

  const size_t need = (3 * kPlane + kAfShorts) * sizeof(short);

  presplit<<<dim3(48 * 16), 256, 0, stream>>>(X, Xh, Xl, XTh);
  if (ws_size >= need) {
    prearr_Abf<<<dim3(16 * 32), 256, 0, stream>>>(A, Af);
    sdgcn_v12<1><<<dim3(48 * 16), 256, 0, stream>>>(X, A, W, gamma, beta, out,
                                                    Xh, Xl, XTh, Af);
  } else {
    sdgcn_v12<0><<<dim3(48 * 16), 256, 0, stream>>>(X, A, W, gamma, beta, out,
                                                    Xh, Xl, XTh, Af);
  }
}